// Round 2
// baseline (275.345 us; speedup 1.0000x reference)
//
#include <hip/hip_runtime.h>

#define BATCH 4
#define VOX 1638400            // 64*160*160
#define VOX4 (VOX / 4)
#define BLOCKS_X 512
#define THREADS 256
#define NACC 17                // A, P[1..8], N[1..8]
#define NTOT (NACC * BATCH)    // 68
#define TOTAL_BLOCKS (BLOCKS_X * BATCH)

__device__ __forceinline__ float p0_of(float d) {
    // p0 = softmax class0 = 1/(1+exp(x1-x0)); d = x1-x0
    float e = __expf(d);
#if __has_builtin(__builtin_amdgcn_rcpf)
    return __builtin_amdgcn_rcpf(1.0f + e);   // v_rcp_f32, ~1ulp, plenty for 1e-2 threshold
#else
    return 1.0f / (1.0f + e);
#endif
}

// ---------------------------------------------------------------------------
// Fused kernel: grid-stride partial reduction + last-block finalize.
// partials layout: [(j*BATCH + b) * BLOCKS_X + bx], j in [0,17)
//   j=0: A (sum p0 over background), j=1..8: P_l (sum p0 over label l),
//   j=9..16: N_l (count of label l). S0, n0 derived in finalize.
// ---------------------------------------------------------------------------
__global__ __launch_bounds__(THREADS) void blob_fused_kernel(
    const float* __restrict__ x, const int* __restrict__ ml,
    float* __restrict__ partials, unsigned int* __restrict__ counter,
    float* __restrict__ out)
{
    const int b  = blockIdx.y;
    const int bx = blockIdx.x;
    const float4* __restrict__ x0v = (const float4*)(x + (size_t)b * 2 * VOX);
    const float4* __restrict__ x1v = (const float4*)(x + (size_t)b * 2 * VOX + VOX);
    const int4*   __restrict__ mlv = (const int4*)(ml + (size_t)b * VOX);

    float accA = 0.f;
    float accP[8], accN[8];
#pragma unroll
    for (int k = 0; k < 8; ++k) { accP[k] = 0.f; accN[k] = 0.f; }

    const int stride = BLOCKS_X * THREADS;
    for (int i = bx * THREADS + threadIdx.x; i < VOX4; i += stride) {
        float4 a0 = x0v[i];
        float4 a1 = x1v[i];
        int4   m  = mlv[i];
        float p0 = p0_of(a1.x - a0.x);
        float p1 = p0_of(a1.y - a0.y);
        float p2 = p0_of(a1.z - a0.z);
        float p3 = p0_of(a1.w - a0.w);
        int orl = m.x | m.y | m.z | m.w;
        if (__ballot(orl != 0) == 0ull) {
            // whole wave: 256 consecutive background voxels (the common case)
            accA += (p0 + p1) + (p2 + p3);
        } else {
            // wave-wide label presence bitmask (bits 0..8), made scalar
            unsigned pres = (1u << m.x) | (1u << m.y) | (1u << m.z) | (1u << m.w);
#pragma unroll
            for (int off = 1; off < 64; off <<= 1) pres |= __shfl_xor((int)pres, off, 64);
            pres = (unsigned)__builtin_amdgcn_readfirstlane((int)pres);

            accA += (m.x == 0 ? p0 : 0.f) + (m.y == 0 ? p1 : 0.f) +
                    (m.z == 0 ? p2 : 0.f) + (m.w == 0 ? p3 : 0.f);
#pragma unroll
            for (int l = 1; l <= 8; ++l) {
                if (pres & (1u << l)) {   // wave-uniform scalar branch
                    float ps = (m.x == l ? p0 : 0.f) + (m.y == l ? p1 : 0.f) +
                               (m.z == l ? p2 : 0.f) + (m.w == l ? p3 : 0.f);
                    float ns = (m.x == l ? 1.f : 0.f) + (m.y == l ? 1.f : 0.f) +
                               (m.z == l ? 1.f : 0.f) + (m.w == l ? 1.f : 0.f);
                    accP[l - 1] += ps;
                    accN[l - 1] += ns;
                }
            }
        }
    }

    // ---- block reduce: wave shuffle -> LDS across 4 waves ----
    float accs[NACC];
    accs[0] = accA;
#pragma unroll
    for (int k = 0; k < 8; ++k) { accs[1 + k] = accP[k]; accs[9 + k] = accN[k]; }

    __shared__ float red[4][NACC];
    const int lane = threadIdx.x & 63;
    const int wave = threadIdx.x >> 6;
#pragma unroll
    for (int j = 0; j < NACC; ++j) {
        float v = accs[j];
        for (int off = 32; off > 0; off >>= 1) v += __shfl_down(v, off, 64);
        if (lane == 0) red[wave][j] = v;
    }
    __syncthreads();
    if (threadIdx.x < NACC) {
        float s = red[0][threadIdx.x] + red[1][threadIdx.x] +
                  red[2][threadIdx.x] + red[3][threadIdx.x];
        partials[((size_t)threadIdx.x * BATCH + b) * BLOCKS_X + bx] = s;
    }

    // ---- last-block finalize ----
    __shared__ unsigned amLast;
    __threadfence();                       // release partials (device scope)
    if (threadIdx.x == 0) {
        unsigned old = atomicAdd(counter, 1u);   // device-scope by default
        amLast = (old == TOTAL_BLOCKS - 1) ? 1u : 0u;
    }
    __syncthreads();
    if (amLast) {
        __threadfence();                   // acquire other blocks' partials
        __shared__ double totals[NTOT];
        // 4 waves, each handles p = wave + 4*r, r in [0,17)
        for (int p = wave; p < NTOT; p += 4) {
            double s = 0.0;
#pragma unroll
            for (int i = 0; i < BLOCKS_X / 64; ++i) {
                float f = __hip_atomic_load(&partials[(size_t)p * BLOCKS_X + lane + i * 64],
                                            __ATOMIC_RELAXED, __HIP_MEMORY_SCOPE_AGENT);
                s += (double)f;
            }
            for (int off = 32; off > 0; off >>= 1) s += __shfl_down(s, off, 64);
            if (lane == 0) totals[p] = s;
        }
        __syncthreads();
        if (threadIdx.x == 0) {
            const double Vd = (double)VOX;
            const double TA = 0.3, TB = 0.7;
            double sum_main = 0.0, sum_blob = 0.0;
            for (int bb = 0; bb < BATCH; ++bb) {
                double A = totals[0 * BATCH + bb];
                double P[8], N[8], SP = 0.0, SN = 0.0;
                for (int k = 0; k < 8; ++k) {
                    P[k] = totals[(1 + k) * BATCH + bb];
                    N[k] = totals[(9 + k) * BATCH + bb];
                    SP += P[k]; SN += N[k];
                }
                double n0 = Vd - SN;
                { // main, class 0 (g = background)
                    double tp = A, fp = SP, fn = n0 - A;
                    sum_main += tp / fmax(tp + TA * fp + TB * fn, 1e-8);
                }
                { // main, class 1 (g = foreground)
                    double tp = SN - SP, fp = n0 - A, fn = SP;
                    sum_main += tp / fmax(tp + TA * fp + TB * fn, 1e-8);
                }
                for (int k = 0; k < 8; ++k) {
                    double mo = SN - N[k];           // other-blob voxels -> p=(.5,.5)
                    { // class 0: g = (L != lab)
                        double tp = A + 0.5 * mo;
                        double fp = P[k];
                        double fn = (Vd - N[k]) - tp;
                        sum_blob += tp / fmax(tp + TA * fp + TB * fn, 1e-8);
                    }
                    { // class 1: g = (L == lab)
                        double tp = N[k] - P[k];
                        double fp = (n0 - A) + 0.5 * mo;
                        double fn = P[k];
                        sum_blob += tp / fmax(tp + TA * fp + TB * fn, 1e-8);
                    }
                }
            }
            out[0] = (float)(-(sum_main / 8.0 + sum_blob / 128.0));
        }
    }
}

extern "C" void kernel_launch(void* const* d_in, const int* in_sizes, int n_in,
                              void* d_out, int out_size, void* d_ws, size_t ws_size,
                              hipStream_t stream) {
    const float* x  = (const float*)d_in[0];
    const int*   ml = (const int*)d_in[1];
    float* out      = (float*)d_out;
    float* partials = (float*)d_ws;                          // NTOT*512 floats = 136 KiB
    unsigned int* counter =
        (unsigned int*)((char*)d_ws + (size_t)NTOT * BLOCKS_X * sizeof(float));

    hipMemsetAsync(counter, 0, sizeof(unsigned int), stream);  // ws is poisoned 0xAA
    dim3 grid(BLOCKS_X, BATCH);
    blob_fused_kernel<<<grid, THREADS, 0, stream>>>(x, ml, partials, counter, out);
}

// Round 3
// 115.452 us; speedup vs baseline: 2.3849x; 2.3849x over previous
//
#include <hip/hip_runtime.h>

#define BATCH 4
#define VOX 1638400            // 64*160*160
#define VOX4 (VOX / 4)
#define BLOCKS_X 256
#define THREADS 256
#define NACC 17                // A, P[1..8], N[1..8]
#define NTOT (NACC * BATCH)    // 68

__device__ __forceinline__ float p0_of(float d) {
    // softmax class0 of 2 classes: p0 = 1/(1+exp(x1-x0)); d = x1-x0
    float e = __expf(d);
    return __builtin_amdgcn_rcpf(1.0f + e);   // ~1ulp; threshold is 1e-2
}

// ---------------------------------------------------------------------------
// Kernel 1: per-(sample, block) partial reductions. No fences, no atomics.
// partials layout: [(j*BATCH + b) * BLOCKS_X + bx], j in [0,17)
//   j=0: A (sum p0 over background), j=1..8: P_l, j=9..16: N_l.
// ---------------------------------------------------------------------------
__global__ __launch_bounds__(THREADS) void blob_reduce_kernel(
    const float* __restrict__ x, const int* __restrict__ ml,
    float* __restrict__ partials)
{
    const int b  = blockIdx.y;
    const int bx = blockIdx.x;
    const float4* __restrict__ x0v = (const float4*)(x + (size_t)b * 2 * VOX);
    const float4* __restrict__ x1v = (const float4*)(x + (size_t)b * 2 * VOX + VOX);
    const int4*   __restrict__ mlv = (const int4*)(ml + (size_t)b * VOX);

    float accA = 0.f;
    float accP[8], accN[8];
#pragma unroll
    for (int k = 0; k < 8; ++k) { accP[k] = 0.f; accN[k] = 0.f; }

    const int stride = BLOCKS_X * THREADS;
    for (int i = bx * THREADS + threadIdx.x; i < VOX4; i += stride) {
        float4 a0 = x0v[i];
        float4 a1 = x1v[i];
        int4   m  = mlv[i];
        float p0 = p0_of(a1.x - a0.x);
        float p1 = p0_of(a1.y - a0.y);
        float p2 = p0_of(a1.z - a0.z);
        float p3 = p0_of(a1.w - a0.w);
        int orl = m.x | m.y | m.z | m.w;
        if (__ballot(orl != 0) == 0ull) {
            // whole wave is background (common case: ~90% of volume)
            accA += (p0 + p1) + (p2 + p3);
        } else {
            accA += (m.x == 0 ? p0 : 0.f) + (m.y == 0 ? p1 : 0.f) +
                    (m.z == 0 ? p2 : 0.f) + (m.w == 0 ? p3 : 0.f);
#pragma unroll
            for (int l = 1; l <= 8; ++l) {
                accP[l - 1] += (m.x == l ? p0 : 0.f) + (m.y == l ? p1 : 0.f) +
                               (m.z == l ? p2 : 0.f) + (m.w == l ? p3 : 0.f);
                accN[l - 1] += (m.x == l ? 1.f : 0.f) + (m.y == l ? 1.f : 0.f) +
                               (m.z == l ? 1.f : 0.f) + (m.w == l ? 1.f : 0.f);
            }
        }
    }

    float accs[NACC];
    accs[0] = accA;
#pragma unroll
    for (int k = 0; k < 8; ++k) { accs[1 + k] = accP[k]; accs[9 + k] = accN[k]; }

    // block reduce: wave shuffle (64 lanes) -> LDS across 4 waves
    __shared__ float red[4][NACC];
    const int lane = threadIdx.x & 63;
    const int wave = threadIdx.x >> 6;
#pragma unroll
    for (int j = 0; j < NACC; ++j) {
        float v = accs[j];
        for (int off = 32; off > 0; off >>= 1) v += __shfl_down(v, off, 64);
        if (lane == 0) red[wave][j] = v;
    }
    __syncthreads();
    if (threadIdx.x < NACC) {
        float s = red[0][threadIdx.x] + red[1][threadIdx.x] +
                  red[2][threadIdx.x] + red[3][threadIdx.x];
        partials[((size_t)threadIdx.x * BATCH + b) * BLOCKS_X + bx] = s;
    }
}

// ---------------------------------------------------------------------------
// Kernel 2: reduce 256 partials per (j,b) in double, closed-form loss.
// ---------------------------------------------------------------------------
__global__ __launch_bounds__(256) void blob_finalize_kernel(
    const float* __restrict__ partials, float* __restrict__ out)
{
    __shared__ double totals[NTOT];   // index p = j*BATCH + b
    const int lane = threadIdx.x & 63;
    const int wave = threadIdx.x >> 6;        // 4 waves

    for (int p = wave; p < NTOT; p += 4) {
        double s = 0.0;
#pragma unroll
        for (int i = 0; i < BLOCKS_X / 64; ++i)
            s += (double)partials[(size_t)p * BLOCKS_X + lane + i * 64];
        for (int off = 32; off > 0; off >>= 1) s += __shfl_down(s, off, 64);
        if (lane == 0) totals[p] = s;
    }
    __syncthreads();

    if (threadIdx.x == 0) {
        const double Vd = (double)VOX;
        const double TA = 0.3, TB = 0.7;
        double sum_main = 0.0, sum_blob = 0.0;
        for (int bb = 0; bb < BATCH; ++bb) {
            double A = totals[0 * BATCH + bb];
            double P[8], N[8], SP = 0.0, SN = 0.0;
            for (int k = 0; k < 8; ++k) {
                P[k] = totals[(1 + k) * BATCH + bb];
                N[k] = totals[(9 + k) * BATCH + bb];
                SP += P[k]; SN += N[k];
            }
            double n0 = Vd - SN;
            { // main, class 0 (g = background)
                double tp = A, fp = SP, fn = n0 - A;
                sum_main += tp / fmax(tp + TA * fp + TB * fn, 1e-8);
            }
            { // main, class 1 (g = foreground)
                double tp = SN - SP, fp = n0 - A, fn = SP;
                sum_main += tp / fmax(tp + TA * fp + TB * fn, 1e-8);
            }
            for (int k = 0; k < 8; ++k) {
                double mo = SN - N[k];           // other-blob voxels -> p=(.5,.5)
                { // class 0: g = (L != lab)
                    double tp = A + 0.5 * mo;
                    double fp = P[k];
                    double fn = (Vd - N[k]) - tp;
                    sum_blob += tp / fmax(tp + TA * fp + TB * fn, 1e-8);
                }
                { // class 1: g = (L == lab)
                    double tp = N[k] - P[k];
                    double fp = (n0 - A) + 0.5 * mo;
                    double fn = P[k];
                    sum_blob += tp / fmax(tp + TA * fp + TB * fn, 1e-8);
                }
            }
        }
        out[0] = (float)(-(sum_main / 8.0 + sum_blob / 128.0));
    }
}

extern "C" void kernel_launch(void* const* d_in, const int* in_sizes, int n_in,
                              void* d_out, int out_size, void* d_ws, size_t ws_size,
                              hipStream_t stream) {
    const float* x  = (const float*)d_in[0];
    const int*   ml = (const int*)d_in[1];
    float* out      = (float*)d_out;
    float* partials = (float*)d_ws;   // NTOT*256 floats = 68 KiB

    dim3 grid(BLOCKS_X, BATCH);
    blob_reduce_kernel<<<grid, THREADS, 0, stream>>>(x, ml, partials);
    blob_finalize_kernel<<<1, 256, 0, stream>>>(partials, out);
}